// Round 3
// baseline (491.699 us; speedup 1.0000x reference)
//
#include <hip/hip_runtime.h>
#include <math.h>

#define H 1024
#define S 20
#define V 50257
#define NBLK 1024
#define NWAVE 4
#define TOTW (NBLK * NWAVE)   // 4096 waves
#define NCHUNK 7              // ceil(V / (TOTW*2))

__device__ __forceinline__ float wave_reduce_sum(float v) {
  #pragma unroll
  for (int off = 32; off > 0; off >>= 1)
    v += __shfl_xor(v, off, 64);
  return v;
}

// grid-wide sync: all NBLK blocks co-resident (guaranteed by __launch_bounds__(256,4)).
__device__ __forceinline__ void gsync(unsigned* cnt, unsigned target) {
  __syncthreads();
  if (threadIdx.x == 0) {
    __threadfence();  // release prior writes to agent scope
    __hip_atomic_fetch_add(cnt, 1u, __ATOMIC_ACQ_REL, __HIP_MEMORY_SCOPE_AGENT);
    while (__hip_atomic_load(cnt, __ATOMIC_ACQUIRE, __HIP_MEMORY_SCOPE_AGENT) < target)
      __builtin_amdgcn_s_sleep(2);
    __threadfence();  // acquire: invalidate stale cached lines
  }
  __syncthreads();
}

__global__ __launch_bounds__(256, 4) void mega(
    const int* __restrict__ token,
    const float* __restrict__ hidden,      // [H]
    const float* __restrict__ enc,         // [S*H]
    const float* __restrict__ embed_table, // [V][H]
    const float* __restrict__ attn_w,      // [H][2H]
    const float* __restrict__ attn_b,      // [H]
    const float* __restrict__ v_w,         // [H]
    const float* __restrict__ w_ih,        // [3H][2H]
    const float* __restrict__ w_hh,        // [3H][H]
    const float* __restrict__ b_ih,        // [3H]
    const float* __restrict__ b_hh,        // [3H]
    const float* __restrict__ out_w,       // [V][H]
    const float* __restrict__ out_b,       // [V]
    float* __restrict__ out,               // [V + H]
    unsigned* __restrict__ cnt,
    float* __restrict__ bpart,             // [S][256]
    float* __restrict__ hnew,              // [H]
    float* __restrict__ pmax,              // [NBLK]
    float* __restrict__ psum)              // [NBLK]
{
  __shared__ float smem[1088];
  const int t = threadIdx.x;
  const int lane = t & 63;
  const int wv = t >> 6;
  const int b = blockIdx.x;

  // ================= Phase A: attention energy (blocks 0..255) =================
  if (b < 256) {
    const int j = b * 4 + wv;
    const float* wrow = attn_w + (size_t)j * (2 * H);
    float4 wlo[4], whi[4], hid4[4];
    #pragma unroll
    for (int q = 0; q < 4; ++q) {
      const int idx = lane + 64 * q;
      wlo[q]  = ((const float4*)wrow)[idx];
      whi[q]  = ((const float4*)(wrow + H))[idx];
      hid4[q] = ((const float4*)hidden)[idx];
    }
    float hp = 0.f;
    #pragma unroll
    for (int q = 0; q < 4; ++q)
      hp += wlo[q].x * hid4[q].x + wlo[q].y * hid4[q].y +
            wlo[q].z * hid4[q].z + wlo[q].w * hid4[q].w;
    hp = wave_reduce_sum(hp);

    float myval = 0.f;
    #pragma unroll
    for (int s = 0; s < S; ++s) {
      const float4* e4 = (const float4*)(enc + s * H);
      float es = 0.f;
      #pragma unroll
      for (int q = 0; q < 4; ++q) {
        const int idx = lane + 64 * q;
        const float4 e = e4[idx];
        es += whi[q].x * e.x + whi[q].y * e.y + whi[q].z * e.z + whi[q].w * e.w;
      }
      es = wave_reduce_sum(es);
      if (lane == s) myval = es;
    }
    if (lane < S)
      smem[wv * S + lane] = tanhf(hp + myval + attn_b[j]) * v_w[j];
    __syncthreads();
    if (wv == 0 && lane < S)
      bpart[lane * 256 + b] =
          smem[lane] + smem[S + lane] + smem[2 * S + lane] + smem[3 * S + lane];
  }

  // ---- pre-issue GRU weight loads (independent of phase A results) ----
  const int tok = *token;
  const float* embed = embed_table + (size_t)tok * H;
  float4 wiv[8], whv[4], xe4[4], hh4[4];
  if (wv < 3) {
    const float* wi = w_ih + (size_t)(wv * H + b) * (2 * H);
    const float* wh = w_hh + (size_t)(wv * H + b) * H;
    #pragma unroll
    for (int q = 0; q < 8; ++q) wiv[q] = ((const float4*)wi)[lane + 64 * q];
    #pragma unroll
    for (int q = 0; q < 4; ++q) whv[q] = ((const float4*)wh)[lane + 64 * q];
    #pragma unroll
    for (int q = 0; q < 4; ++q) xe4[q] = ((const float4*)embed)[lane + 64 * q];
    #pragma unroll
    for (int q = 0; q < 4; ++q) hh4[q] = ((const float4*)hidden)[lane + 64 * q];
  }

  gsync(cnt, NBLK);

  // ================= Phase B: softmax + context (redundant) + GRU (j = b) =====
  {
    float* scores_sh = smem;        // [20]
    float* attn_sh   = smem + 20;   // [20]
    float* gred      = smem + 40;   // [8]
    float* wsh       = smem + 64;   // [1024] context

    for (int s = wv; s < S; s += 4) {
      const float4 p = ((const float4*)(bpart + s * 256))[lane];
      float v = p.x + p.y + p.z + p.w;
      v = wave_reduce_sum(v);
      if (lane == 0) scores_sh[s] = v;
    }
    __syncthreads();
    if (t == 0) {
      float m = -1e30f;
      for (int s = 0; s < S; ++s) m = fmaxf(m, scores_sh[s]);
      float sum = 0.f;
      for (int s = 0; s < S; ++s) {
        const float e = expf(scores_sh[s] - m);
        attn_sh[s] = e;
        sum += e;
      }
      const float inv = 1.f / sum;
      for (int s = 0; s < S; ++s) attn_sh[s] *= inv;
    }
    __syncthreads();
    for (int h = t; h < H; h += 256) {
      float acc = 0.f;
      #pragma unroll
      for (int s = 0; s < S; ++s) acc += attn_sh[s] * enc[s * H + h];
      wsh[h] = acc;
    }
    __syncthreads();

    if (wv < 3) {
      float a = 0.f;
      #pragma unroll
      for (int q = 0; q < 4; ++q) {
        const float4 w = wiv[q];
        a += w.x * xe4[q].x + w.y * xe4[q].y + w.z * xe4[q].z + w.w * xe4[q].w;
      }
      #pragma unroll
      for (int q = 0; q < 4; ++q) {
        const float4 w = wiv[q + 4];
        const float4 x = ((const float4*)wsh)[lane + 64 * q];
        a += w.x * x.x + w.y * x.y + w.z * x.z + w.w * x.w;
      }
      a = wave_reduce_sum(a);
      float c = 0.f;
      #pragma unroll
      for (int q = 0; q < 4; ++q) {
        const float4 w = whv[q];
        c += w.x * hh4[q].x + w.y * hh4[q].y + w.z * hh4[q].z + w.w * hh4[q].w;
      }
      c = wave_reduce_sum(c);
      if (lane == 0) { gred[wv] = a; gred[4 + wv] = c; }
    }
    __syncthreads();
    if (t == 0) {
      const float i_r = gred[0] + b_ih[b];
      const float i_z = gred[1] + b_ih[H + b];
      const float i_n = gred[2] + b_ih[2 * H + b];
      const float h_r = gred[4] + b_hh[b];
      const float h_z = gred[5] + b_hh[H + b];
      const float h_n = gred[6] + b_hh[2 * H + b];
      const float r = 1.f / (1.f + expf(-(i_r + h_r)));
      const float z = 1.f / (1.f + expf(-(i_z + h_z)));
      const float n = tanhf(i_n + r * h_n);
      const float hn = (1.f - z) * n + z * hidden[b];
      hnew[b] = hn;
      out[V + b] = hn;
    }
  }

  gsync(cnt, 2 * NBLK);

  // ================= Phase C: logits in registers + per-block stats ===========
  float4 h4[4];
  #pragma unroll
  for (int q = 0; q < 4; ++q) h4[q] = ((const float4*)hnew)[lane + 64 * q];

  const int w = b * NWAVE + wv;   // global wave id, wave-uniform
  float val0[NCHUNK], val1[NCHUNK];
  #pragma unroll
  for (int c = 0; c < NCHUNK; ++c) {
    const int v0 = (c * TOTW + w) * 2;
    const int v1 = v0 + 1;
    val0[c] = -INFINITY;
    val1[c] = -INFINITY;
    if (v0 < V) {
      const float4* r0 = (const float4*)(out_w + (size_t)v0 * H);
      float a0 = 0.f, a1 = 0.f;
      if (v1 < V) {
        const float4* r1 = (const float4*)(out_w + (size_t)v1 * H);
        #pragma unroll
        for (int q = 0; q < 4; ++q) {
          const int idx = lane + 64 * q;
          const float4 w0 = r0[idx];
          const float4 w1 = r1[idx];
          a0 += w0.x * h4[q].x + w0.y * h4[q].y + w0.z * h4[q].z + w0.w * h4[q].w;
          a1 += w1.x * h4[q].x + w1.y * h4[q].y + w1.z * h4[q].z + w1.w * h4[q].w;
        }
        a0 = wave_reduce_sum(a0);
        a1 = wave_reduce_sum(a1);
        val0[c] = a0 + out_b[v0];
        val1[c] = a1 + out_b[v1];
      } else {
        #pragma unroll
        for (int q = 0; q < 4; ++q) {
          const int idx = lane + 64 * q;
          const float4 w0 = r0[idx];
          a0 += w0.x * h4[q].x + w0.y * h4[q].y + w0.z * h4[q].z + w0.w * h4[q].w;
        }
        a0 = wave_reduce_sum(a0);
        val0[c] = a0 + out_b[v0];
      }
    }
  }

  // wave stats (all lanes hold identical vals)
  {
    float m = -INFINITY;
    #pragma unroll
    for (int c = 0; c < NCHUNK; ++c)
      m = fmaxf(m, fmaxf(val0[c], val1[c]));
    float sum = 0.f;
    #pragma unroll
    for (int c = 0; c < NCHUNK; ++c) {
      sum += expf(val0[c] - m);
      sum += expf(val1[c] - m);
    }
    if (lane == 0) { smem[wv] = m; smem[4 + wv] = sum; }
  }
  __syncthreads();
  if (t == 0) {
    float M = smem[0], Ss = smem[4];
    #pragma unroll
    for (int i = 1; i < 4; ++i) {
      const float m2 = smem[i], s2 = smem[4 + i];
      const float M2 = fmaxf(M, m2);
      Ss = Ss * expf(M - M2) + s2 * expf(m2 - M2);
      M = M2;
    }
    pmax[b] = M;
    psum[b] = Ss;
  }

  gsync(cnt, 3 * NBLK);

  // ================= Phase D: redundant global reduce + final write ===========
  float dm = -INFINITY, dsv = 0.f;
  #pragma unroll
  for (int r = 0; r < 4; ++r) {
    const int i = t + r * 256;
    const float pm = pmax[i];
    const float ps = psum[i];
    const float M2 = fmaxf(dm, pm);
    dsv = dsv * expf(dm - M2) + ps * expf(pm - M2);
    dm = M2;
  }
  #pragma unroll
  for (int off = 32; off > 0; off >>= 1) {
    const float m2 = __shfl_xor(dm, off, 64);
    const float s2 = __shfl_xor(dsv, off, 64);
    const float M2 = fmaxf(dm, m2);
    dsv = dsv * expf(dm - M2) + s2 * expf(m2 - M2);
    dm = M2;
  }
  if (lane == 0) { smem[8 + wv] = dm; smem[12 + wv] = dsv; }
  __syncthreads();
  if (t == 0) {
    float M = smem[8], Ss = smem[12];
    #pragma unroll
    for (int i = 1; i < 4; ++i) {
      const float m2 = smem[8 + i], s2 = smem[12 + i];
      const float M2 = fmaxf(M, m2);
      Ss = Ss * expf(M - M2) + s2 * expf(m2 - M2);
      M = M2;
    }
    smem[16] = M + logf(Ss);
  }
  __syncthreads();
  const float T = smem[16];

  if (lane == 0) {
    #pragma unroll
    for (int c = 0; c < NCHUNK; ++c) {
      const int v0 = (c * TOTW + w) * 2;
      if (v0 < V) {
        if (v0 + 1 < V) {
          float2 o;
          o.x = val0[c] - T;
          o.y = val1[c] - T;
          *reinterpret_cast<float2*>(out + v0) = o;
        } else {
          out[v0] = val0[c] - T;
        }
      }
    }
  }
}

extern "C" void kernel_launch(void* const* d_in, const int* in_sizes, int n_in,
                              void* d_out, int out_size, void* d_ws, size_t ws_size,
                              hipStream_t stream) {
  const int*   token       = (const int*)d_in[0];
  const float* hidden      = (const float*)d_in[1];
  const float* enc         = (const float*)d_in[2];
  const float* embed_table = (const float*)d_in[3];
  const float* attn_w      = (const float*)d_in[4];
  const float* attn_b      = (const float*)d_in[5];
  const float* v_w         = (const float*)d_in[6];
  const float* w_ih        = (const float*)d_in[7];
  const float* w_hh        = (const float*)d_in[8];
  const float* b_ih        = (const float*)d_in[9];
  const float* b_hh        = (const float*)d_in[10];
  const float* out_w       = (const float*)d_in[11];
  const float* out_b       = (const float*)d_in[12];
  float* out = (float*)d_out;
  float* ws  = (float*)d_ws;

  // ws layout (floats): [0..15] counter area, bpart@16 (5120), hnew@5136 (1024),
  // pmax@6160 (1024), psum@7184 (1024)  -> ~33 KB total
  unsigned* cnt = (unsigned*)ws;
  float* bpart = ws + 16;
  float* hnew  = ws + 5136;
  float* pmax  = ws + 6160;
  float* psum  = ws + 7184;

  hipMemsetAsync(d_ws, 0, 64, stream);  // reset sync counter each call (deterministic)

  mega<<<NBLK, 256, 0, stream>>>(token, hidden, enc, embed_table, attn_w, attn_b,
                                 v_w, w_ih, w_hh, b_ih, b_hh, out_w, out_b,
                                 out, cnt, bpart, hnew, pmax, psum);
}

// Round 4
// 64.495 us; speedup vs baseline: 7.6238x; 7.6238x over previous
//
#include <hip/hip_runtime.h>
#include <math.h>

#define H 1024
#define S 20
#define V 50257

__device__ __forceinline__ float wave_reduce_sum(float v) {
  #pragma unroll
  for (int off = 32; off > 0; off >>= 1)
    v += __shfl_xor(v, off, 64);
  return v;
}

// ============ kA: independent streaming work ============
// b in [0,256):    attention energy -> bpart[S][256]
// b in [256,1024): gie[W] = dot(w_ih[W][0:H], embed) + b_ih[W],  W=(b-256)*4+wv
// b in [1024,1792): ghv[W] = dot(w_hh[W], hidden) + b_hh[W]
__global__ __launch_bounds__(256) void kA(
    const int* __restrict__ token,
    const float* __restrict__ hidden,
    const float* __restrict__ enc,
    const float* __restrict__ embed_table,
    const float* __restrict__ attn_w,
    const float* __restrict__ attn_b,
    const float* __restrict__ v_w,
    const float* __restrict__ w_ih,
    const float* __restrict__ w_hh,
    const float* __restrict__ b_ih,
    const float* __restrict__ b_hh,
    float* __restrict__ bpart,   // [S][256]
    float* __restrict__ gie,     // [3H]
    float* __restrict__ ghv)     // [3H]
{
  __shared__ float esh[4][S];
  const int t = threadIdx.x;
  const int lane = t & 63;
  const int wv = t >> 6;
  const int b = blockIdx.x;

  if (b < 256) {
    const int j = b * 4 + wv;
    const float* wrow = attn_w + (size_t)j * (2 * H);
    float4 wlo[4], whi[4], hid4[4];
    #pragma unroll
    for (int q = 0; q < 4; ++q) {
      const int idx = lane + 64 * q;
      wlo[q]  = ((const float4*)wrow)[idx];
      whi[q]  = ((const float4*)(wrow + H))[idx];
      hid4[q] = ((const float4*)hidden)[idx];
    }
    float hp = 0.f;
    #pragma unroll
    for (int q = 0; q < 4; ++q)
      hp += wlo[q].x * hid4[q].x + wlo[q].y * hid4[q].y +
            wlo[q].z * hid4[q].z + wlo[q].w * hid4[q].w;
    hp = wave_reduce_sum(hp);

    float myval = 0.f;
    #pragma unroll
    for (int s = 0; s < S; ++s) {
      const float4* e4 = (const float4*)(enc + s * H);
      float es = 0.f;
      #pragma unroll
      for (int q = 0; q < 4; ++q) {
        const int idx = lane + 64 * q;
        const float4 e = e4[idx];
        es += whi[q].x * e.x + whi[q].y * e.y + whi[q].z * e.z + whi[q].w * e.w;
      }
      es = wave_reduce_sum(es);
      if (lane == s) myval = es;
    }
    if (lane < S)
      esh[wv][lane] = tanhf(hp + myval + attn_b[j]) * v_w[j];
    __syncthreads();
    if (wv == 0 && lane < S)
      bpart[lane * 256 + b] =
          esh[0][lane] + esh[1][lane] + esh[2][lane] + esh[3][lane];
  } else if (b < 1024) {
    const int W = (b - 256) * 4 + wv;
    const float* wr = w_ih + (size_t)W * (2 * H);
    const float* embed = embed_table + (size_t)(*token) * H;
    float a = 0.f;
    #pragma unroll
    for (int q = 0; q < 4; ++q) {
      const int idx = lane + 64 * q;
      const float4 w = ((const float4*)wr)[idx];
      const float4 e = ((const float4*)embed)[idx];
      a += w.x * e.x + w.y * e.y + w.z * e.z + w.w * e.w;
    }
    a = wave_reduce_sum(a);
    if (lane == 0) gie[W] = a + b_ih[W];
  } else {
    const int W = (b - 1024) * 4 + wv;
    const float* wr = w_hh + (size_t)W * H;
    float a = 0.f;
    #pragma unroll
    for (int q = 0; q < 4; ++q) {
      const int idx = lane + 64 * q;
      const float4 w = ((const float4*)wr)[idx];
      const float4 h = ((const float4*)hidden)[idx];
      a += w.x * h.x + w.y * h.y + w.z * h.z + w.w * h.w;
    }
    a = wave_reduce_sum(a);
    if (lane == 0) ghv[W] = a + b_hh[W];
  }
}

// ============ kB: redundant softmax+context, then context half of gi ========
// 768 blocks; wave W = b*4+wv in [0,3072): gi_full[W] = gie[W] + dot(w_ih[W][H:2H], ctx)
__global__ __launch_bounds__(256) void kB(
    const float* __restrict__ enc,
    const float* __restrict__ bpart,
    const float* __restrict__ w_ih,
    const float* __restrict__ gie,
    float* __restrict__ gi_full)
{
  __shared__ float scores_sh[S];
  __shared__ float attn_sh[S];
  __shared__ float wsh[H];
  const int t = threadIdx.x;
  const int lane = t & 63;
  const int wv = t >> 6;

  for (int s = wv; s < S; s += 4) {
    const float4 p = ((const float4*)(bpart + s * 256))[lane];
    float v = p.x + p.y + p.z + p.w;
    v = wave_reduce_sum(v);
    if (lane == 0) scores_sh[s] = v;
  }
  __syncthreads();
  if (t == 0) {
    float m = -1e30f;
    for (int s = 0; s < S; ++s) m = fmaxf(m, scores_sh[s]);
    float sum = 0.f;
    for (int s = 0; s < S; ++s) {
      const float e = expf(scores_sh[s] - m);
      attn_sh[s] = e;
      sum += e;
    }
    const float inv = 1.f / sum;
    for (int s = 0; s < S; ++s) attn_sh[s] *= inv;
  }
  __syncthreads();
  for (int h = t; h < H; h += 256) {
    float acc = 0.f;
    #pragma unroll
    for (int s = 0; s < S; ++s) acc += attn_sh[s] * enc[s * H + h];
    wsh[h] = acc;
  }
  __syncthreads();

  const int W = blockIdx.x * 4 + wv;
  const float* wr = w_ih + (size_t)W * (2 * H) + H;
  float a = 0.f;
  #pragma unroll
  for (int q = 0; q < 4; ++q) {
    const int idx = lane + 64 * q;
    const float4 w = ((const float4*)wr)[idx];
    const float4 x = ((const float4*)wsh)[idx];
    a += w.x * x.x + w.y * x.y + w.z * x.z + w.w * x.w;
  }
  a = wave_reduce_sum(a);
  if (lane == 0) gi_full[W] = gie[W] + a;
}

// ============ kC: redundant hnew + logits (4 rows/wave) + block stats =======
// 1571 blocks x 512 threads (8 waves); wave W = b*8+wv covers rows 4W..4W+3.
__global__ __launch_bounds__(512) void kC(
    const float* __restrict__ hidden,
    const float* __restrict__ gi_full,  // [3H]
    const float* __restrict__ ghv,      // [3H]
    const float* __restrict__ out_w,    // [V][H]
    const float* __restrict__ out_b,    // [V]
    float* __restrict__ out,            // [V + H]
    float* __restrict__ pmax,
    float* __restrict__ psum)
{
  __shared__ float hnew_lds[H];
  __shared__ float stat_m[8];
  __shared__ float stat_s[8];
  const int t = threadIdx.x;
  const int lane = t & 63;
  const int wv = t >> 6;
  const int b = blockIdx.x;

  // front: redundant GRU gate combine -> hnew (L2-hot reads)
  #pragma unroll
  for (int r = 0; r < 2; ++r) {
    const int j = t + r * 512;
    const float i_r = gi_full[j];
    const float i_z = gi_full[H + j];
    const float i_n = gi_full[2 * H + j];
    const float h_r = ghv[j];
    const float h_z = ghv[H + j];
    const float h_n = ghv[2 * H + j];
    const float rr = 1.f / (1.f + expf(-(i_r + h_r)));
    const float zz = 1.f / (1.f + expf(-(i_z + h_z)));
    const float nn = tanhf(i_n + rr * h_n);
    const float hn = (1.f - zz) * nn + zz * hidden[j];
    hnew_lds[j] = hn;
    if (b == 0) out[V + j] = hn;
  }
  __syncthreads();

  float4 h4[4];
  #pragma unroll
  for (int q = 0; q < 4; ++q)
    h4[q] = ((const float4*)hnew_lds)[lane + 64 * q];

  const int W = b * 8 + wv;
  const int vbase = W * 4;
  const int v0 = (vbase < V - 1) ? vbase : (V - 1);
  const int v1 = (vbase + 1 < V) ? vbase + 1 : (V - 1);
  const int v2 = (vbase + 2 < V) ? vbase + 2 : (V - 1);
  const int v3 = (vbase + 3 < V) ? vbase + 3 : (V - 1);
  const float4* r0 = (const float4*)(out_w + (size_t)v0 * H);
  const float4* r1 = (const float4*)(out_w + (size_t)v1 * H);
  const float4* r2 = (const float4*)(out_w + (size_t)v2 * H);
  const float4* r3 = (const float4*)(out_w + (size_t)v3 * H);
  float a0 = 0.f, a1 = 0.f, a2 = 0.f, a3 = 0.f;
  #pragma unroll
  for (int q = 0; q < 4; ++q) {
    const int idx = lane + 64 * q;
    const float4 w0 = r0[idx];
    const float4 w1 = r1[idx];
    const float4 w2 = r2[idx];
    const float4 w3 = r3[idx];
    a0 += w0.x * h4[q].x + w0.y * h4[q].y + w0.z * h4[q].z + w0.w * h4[q].w;
    a1 += w1.x * h4[q].x + w1.y * h4[q].y + w1.z * h4[q].z + w1.w * h4[q].w;
    a2 += w2.x * h4[q].x + w2.y * h4[q].y + w2.z * h4[q].z + w2.w * h4[q].w;
    a3 += w3.x * h4[q].x + w3.y * h4[q].y + w3.z * h4[q].z + w3.w * h4[q].w;
  }
  a0 = wave_reduce_sum(a0);
  a1 = wave_reduce_sum(a1);
  a2 = wave_reduce_sum(a2);
  a3 = wave_reduce_sum(a3);
  float val0 = (vbase     < V) ? a0 + out_b[v0] : -INFINITY;
  float val1 = (vbase + 1 < V) ? a1 + out_b[v1] : -INFINITY;
  float val2 = (vbase + 2 < V) ? a2 + out_b[v2] : -INFINITY;
  float val3 = (vbase + 3 < V) ? a3 + out_b[v3] : -INFINITY;

  if (lane == 0) {
    if (vbase + 3 < V) {
      float4 o; o.x = val0; o.y = val1; o.z = val2; o.w = val3;
      *reinterpret_cast<float4*>(out + vbase) = o;
    } else {
      if (vbase     < V) out[vbase]     = val0;
      if (vbase + 1 < V) out[vbase + 1] = val1;
      if (vbase + 2 < V) out[vbase + 2] = val2;
      if (vbase + 3 < V) out[vbase + 3] = val3;
    }
  }

  float m = fmaxf(fmaxf(val0, val1), fmaxf(val2, val3));
  float s = 0.f;
  if (m != -INFINITY) {
    s = expf(val0 - m) + expf(val1 - m) + expf(val2 - m) + expf(val3 - m);
  }
  if (lane == 0) { stat_m[wv] = m; stat_s[wv] = s; }
  __syncthreads();
  if (t == 0) {
    float M = stat_m[0], Ss = stat_s[0];
    #pragma unroll
    for (int i = 1; i < 8; ++i) {
      const float m2 = stat_m[i], s2 = stat_s[i];
      const float M2 = fmaxf(M, m2);
      Ss = Ss * expf(M - M2) + s2 * expf(m2 - M2);
      M = M2;
    }
    pmax[b] = M;
    psum[b] = Ss;
  }
}

// ============ kD: block-redundant stat reduce + subtract ============
// 50 blocks x 1024 threads.
__global__ __launch_bounds__(1024) void kD(
    const float* __restrict__ pmax,
    const float* __restrict__ psum, int n,
    float* __restrict__ out)
{
  __shared__ float sm[16];
  __shared__ float ss[16];
  __shared__ float Tsh;
  const int t = threadIdx.x, lane = t & 63, wv = t >> 6;

  float dm = -INFINITY, dsv = 0.f;
  for (int i = t; i < n; i += 1024) {
    const float pm = pmax[i];
    const float ps = psum[i];
    const float M2 = fmaxf(dm, pm);
    dsv = dsv * expf(dm - M2) + ps * expf(pm - M2);
    dm = M2;
  }
  #pragma unroll
  for (int off = 32; off > 0; off >>= 1) {
    const float m2 = __shfl_xor(dm, off, 64);
    const float s2 = __shfl_xor(dsv, off, 64);
    const float M2 = fmaxf(dm, m2);
    dsv = dsv * expf(dm - M2) + s2 * expf(m2 - M2);
    dm = M2;
  }
  if (lane == 0) { sm[wv] = dm; ss[wv] = dsv; }
  __syncthreads();
  if (t == 0) {
    float M = sm[0], Ss = ss[0];
    #pragma unroll
    for (int i = 1; i < 16; ++i) {
      const float m2 = sm[i], s2 = ss[i];
      const float M2 = fmaxf(M, m2);
      Ss = Ss * expf(M - M2) + s2 * expf(m2 - M2);
      M = M2;
    }
    Tsh = M + logf(Ss);
  }
  __syncthreads();
  const float T = Tsh;
  const int i = blockIdx.x * 1024 + t;
  if (i < V) out[i] -= T;
}

extern "C" void kernel_launch(void* const* d_in, const int* in_sizes, int n_in,
                              void* d_out, int out_size, void* d_ws, size_t ws_size,
                              hipStream_t stream) {
  const int*   token       = (const int*)d_in[0];
  const float* hidden      = (const float*)d_in[1];
  const float* enc         = (const float*)d_in[2];
  const float* embed_table = (const float*)d_in[3];
  const float* attn_w      = (const float*)d_in[4];
  const float* attn_b      = (const float*)d_in[5];
  const float* v_w         = (const float*)d_in[6];
  const float* w_ih        = (const float*)d_in[7];
  const float* w_hh        = (const float*)d_in[8];
  const float* b_ih        = (const float*)d_in[9];
  const float* b_hh        = (const float*)d_in[10];
  const float* out_w       = (const float*)d_in[11];
  const float* out_b       = (const float*)d_in[12];
  float* out = (float*)d_out;
  float* ws  = (float*)d_ws;

  // ws layout (floats)
  float* bpart   = ws;           // 5120
  float* gie     = ws + 5120;    // 3072
  float* ghv     = ws + 8192;    // 3072
  float* gi_full = ws + 11264;   // 3072
  float* pmax    = ws + 14336;   // 1571 (pad 1600)
  float* psum    = ws + 15936;   // 1571

  const int nblkC = (V + 31) / 32;   // 1571 blocks, 32 rows each

  kA<<<1792, 256, 0, stream>>>(token, hidden, enc, embed_table, attn_w, attn_b,
                               v_w, w_ih, w_hh, b_ih, b_hh, bpart, gie, ghv);
  kB<<<768, 256, 0, stream>>>(enc, bpart, w_ih, gie, gi_full);
  kC<<<nblkC, 512, 0, stream>>>(hidden, gi_full, ghv, out_w, out_b, out, pmax, psum);
  kD<<<(V + 1023) / 1024, 1024, 0, stream>>>(pmax, psum, nblkC, out);
}

// Round 6
// 60.840 us; speedup vs baseline: 8.0818x; 1.0601x over previous
//
#include <hip/hip_runtime.h>
#include <math.h>

#define H 1024
#define S 20
#define V 50257
#define NGRP ((V + 3) / 4)        // 12565 row-groups of 4
#define KC_BLOCKS 512
#define KC_WAVES (KC_BLOCKS * 8)  // 4096 waves

__device__ __forceinline__ float wave_reduce_sum(float v) {
  #pragma unroll
  for (int off = 32; off > 0; off >>= 1)
    v += __shfl_xor(v, off, 64);
  return v;
}

// ============ kA: independent streaming work (32 MB) ============
// b in [0,256):    attention energy -> bpart[S][256]
// b in [256,1024): gie[W] = dot(w_ih[W][0:H], embed) + b_ih[W],  W=(b-256)*4+wv
// b in [1024,1792): ghv[W] = dot(w_hh[W], hidden) + b_hh[W]
__global__ __launch_bounds__(256) void kA(
    const int* __restrict__ token,
    const float* __restrict__ hidden,
    const float* __restrict__ enc,
    const float* __restrict__ embed_table,
    const float* __restrict__ attn_w,
    const float* __restrict__ attn_b,
    const float* __restrict__ v_w,
    const float* __restrict__ w_ih,
    const float* __restrict__ w_hh,
    const float* __restrict__ b_ih,
    const float* __restrict__ b_hh,
    float* __restrict__ bpart,   // [S][256]
    float* __restrict__ gie,     // [3H]
    float* __restrict__ ghv)     // [3H]
{
  __shared__ float esh[4][S];
  const int t = threadIdx.x;
  const int lane = t & 63;
  const int wv = t >> 6;
  const int b = blockIdx.x;

  if (b < 256) {
    const int j = b * 4 + wv;
    const float* wrow = attn_w + (size_t)j * (2 * H);
    float4 wlo[4], whi[4], hid4[4];
    #pragma unroll
    for (int q = 0; q < 4; ++q) {
      const int idx = lane + 64 * q;
      wlo[q]  = ((const float4*)wrow)[idx];
      whi[q]  = ((const float4*)(wrow + H))[idx];
      hid4[q] = ((const float4*)hidden)[idx];
    }
    float hp = 0.f;
    #pragma unroll
    for (int q = 0; q < 4; ++q)
      hp += wlo[q].x * hid4[q].x + wlo[q].y * hid4[q].y +
            wlo[q].z * hid4[q].z + wlo[q].w * hid4[q].w;
    hp = wave_reduce_sum(hp);

    float myval = 0.f;
    #pragma unroll
    for (int s = 0; s < S; ++s) {
      const float4* e4 = (const float4*)(enc + s * H);
      float es = 0.f;
      #pragma unroll
      for (int q = 0; q < 4; ++q) {
        const int idx = lane + 64 * q;
        const float4 e = e4[idx];
        es += whi[q].x * e.x + whi[q].y * e.y + whi[q].z * e.z + whi[q].w * e.w;
      }
      es = wave_reduce_sum(es);
      if (lane == s) myval = es;
    }
    if (lane < S)
      esh[wv][lane] = tanhf(hp + myval + attn_b[j]) * v_w[j];
    __syncthreads();
    if (wv == 0 && lane < S)
      bpart[lane * 256 + b] =
          esh[0][lane] + esh[1][lane] + esh[2][lane] + esh[3][lane];
  } else if (b < 1024) {
    const int W = (b - 256) * 4 + wv;
    const float* wr = w_ih + (size_t)W * (2 * H);
    const float* embed = embed_table + (size_t)(*token) * H;
    float a = 0.f;
    #pragma unroll
    for (int q = 0; q < 4; ++q) {
      const int idx = lane + 64 * q;
      const float4 w = ((const float4*)wr)[idx];
      const float4 e = ((const float4*)embed)[idx];
      a += w.x * e.x + w.y * e.y + w.z * e.z + w.w * e.w;
    }
    a = wave_reduce_sum(a);
    if (lane == 0) gie[W] = a + b_ih[W];
  } else {
    const int W = (b - 1024) * 4 + wv;
    const float* wr = w_hh + (size_t)W * H;
    float a = 0.f;
    #pragma unroll
    for (int q = 0; q < 4; ++q) {
      const int idx = lane + 64 * q;
      const float4 w = ((const float4*)wr)[idx];
      const float4 h = ((const float4*)hidden)[idx];
      a += w.x * h.x + w.y * h.y + w.z * h.z + w.w * h.w;
    }
    a = wave_reduce_sum(a);
    if (lane == 0) ghv[W] = a + b_hh[W];
  }
}

// ============ kB: redundant softmax+context, 3 ctx rows/wave, gates -> hnew ==
// 256 blocks x 256; wave wv owns j = b*4+wv; computes gi_ctx for rows
// {j, H+j, 2H+j} of w_ih[:,H:2H] and finishes hnew[j].
__global__ __launch_bounds__(256) void kB(
    const float* __restrict__ enc,
    const float* __restrict__ bpart,
    const float* __restrict__ w_ih,
    const float* __restrict__ gie,
    const float* __restrict__ ghv,
    const float* __restrict__ hidden,
    float* __restrict__ hnew,
    float* __restrict__ out)      // out[V..V+H) gets hnew
{
  __shared__ float scores_sh[S];
  __shared__ float attn_sh[S];
  __shared__ float wsh[H];
  const int t = threadIdx.x;
  const int lane = t & 63;
  const int wv = t >> 6;
  const int j = blockIdx.x * 4 + wv;

  for (int s = wv; s < S; s += 4) {
    const float4 p = ((const float4*)(bpart + s * 256))[lane];
    float v = p.x + p.y + p.z + p.w;
    v = wave_reduce_sum(v);
    if (lane == 0) scores_sh[s] = v;
  }
  __syncthreads();
  if (t == 0) {
    float m = -1e30f;
    for (int s = 0; s < S; ++s) m = fmaxf(m, scores_sh[s]);
    float sum = 0.f;
    for (int s = 0; s < S; ++s) {
      const float e = expf(scores_sh[s] - m);
      attn_sh[s] = e;
      sum += e;
    }
    const float inv = 1.f / sum;
    for (int s = 0; s < S; ++s) attn_sh[s] *= inv;
  }
  __syncthreads();
  for (int h = t; h < H; h += 256) {
    float acc = 0.f;
    #pragma unroll
    for (int s = 0; s < S; ++s) acc += attn_sh[s] * enc[s * H + h];
    wsh[h] = acc;
  }
  __syncthreads();

  // 3 context-half rows for gates r,z,n of output j
  float4 c4[4];
  #pragma unroll
  for (int q = 0; q < 4; ++q) c4[q] = ((const float4*)wsh)[lane + 64 * q];

  float gict[3];
  #pragma unroll
  for (int g = 0; g < 3; ++g) {
    const float* wr = w_ih + (size_t)(g * H + j) * (2 * H) + H;
    float a = 0.f;
    #pragma unroll
    for (int q = 0; q < 4; ++q) {
      const float4 w = ((const float4*)wr)[lane + 64 * q];
      a += w.x * c4[q].x + w.y * c4[q].y + w.z * c4[q].z + w.w * c4[q].w;
    }
    gict[g] = wave_reduce_sum(a);
  }

  if (lane == 0) {
    const float i_r = gie[j]         + gict[0];
    const float i_z = gie[H + j]     + gict[1];
    const float i_n = gie[2 * H + j] + gict[2];
    const float h_r = ghv[j];
    const float h_z = ghv[H + j];
    const float h_n = ghv[2 * H + j];
    const float r = 1.f / (1.f + expf(-(i_r + h_r)));
    const float z = 1.f / (1.f + expf(-(i_z + h_z)));
    const float n = tanhf(i_n + r * h_n);
    const float hn = (1.f - z) * n + z * hidden[j];
    hnew[j] = hn;
    out[V + j] = hn;
  }
}

// ============ kC: persistent grid-stride logits + per-block stats ============
// 512 blocks x 512 threads; wave gw handles row-groups gw, gw+4096, ...
__global__ __launch_bounds__(512) void kC(
    const float* __restrict__ hnew,
    const float* __restrict__ out_w,    // [V][H]
    const float* __restrict__ out_b,    // [V]
    float* __restrict__ out,            // logits
    float* __restrict__ pmax,           // [KC_BLOCKS]
    float* __restrict__ psum)           // [KC_BLOCKS]
{
  __shared__ float stat_m[8];
  __shared__ float stat_s[8];
  const int t = threadIdx.x;
  const int lane = t & 63;
  const int wv = t >> 6;
  const int b = blockIdx.x;
  const int gw = b * 8 + wv;

  float4 h4[4];
  #pragma unroll
  for (int q = 0; q < 4; ++q)
    h4[q] = ((const float4*)hnew)[lane + 64 * q];

  float wm = -INFINITY, wsum = 0.f;

  for (int grp = gw; grp < NGRP; grp += KC_WAVES) {
    const int vbase = grp * 4;
    const int v0 = vbase;
    const int v1 = (vbase + 1 < V) ? vbase + 1 : (V - 1);
    const int v2 = (vbase + 2 < V) ? vbase + 2 : (V - 1);
    const int v3 = (vbase + 3 < V) ? vbase + 3 : (V - 1);
    const float4* r0 = (const float4*)(out_w + (size_t)v0 * H);
    const float4* r1 = (const float4*)(out_w + (size_t)v1 * H);
    const float4* r2 = (const float4*)(out_w + (size_t)v2 * H);
    const float4* r3 = (const float4*)(out_w + (size_t)v3 * H);
    float a0 = 0.f, a1 = 0.f, a2 = 0.f, a3 = 0.f;
    #pragma unroll
    for (int q = 0; q < 4; ++q) {
      const int idx = lane + 64 * q;
      const float4 w0 = r0[idx];
      const float4 w1 = r1[idx];
      const float4 w2 = r2[idx];
      const float4 w3 = r3[idx];
      a0 += w0.x * h4[q].x + w0.y * h4[q].y + w0.z * h4[q].z + w0.w * h4[q].w;
      a1 += w1.x * h4[q].x + w1.y * h4[q].y + w1.z * h4[q].z + w1.w * h4[q].w;
      a2 += w2.x * h4[q].x + w2.y * h4[q].y + w2.z * h4[q].z + w2.w * h4[q].w;
      a3 += w3.x * h4[q].x + w3.y * h4[q].y + w3.z * h4[q].z + w3.w * h4[q].w;
    }
    a0 = wave_reduce_sum(a0);
    a1 = wave_reduce_sum(a1);
    a2 = wave_reduce_sum(a2);
    a3 = wave_reduce_sum(a3);
    const float val0 = a0 + out_b[v0];
    const float val1 = (vbase + 1 < V) ? a1 + out_b[v1] : -INFINITY;
    const float val2 = (vbase + 2 < V) ? a2 + out_b[v2] : -INFINITY;
    const float val3 = (vbase + 3 < V) ? a3 + out_b[v3] : -INFINITY;

    if (lane == 0) {
      if (vbase + 3 < V) {
        float4 o; o.x = val0; o.y = val1; o.z = val2; o.w = val3;
        *reinterpret_cast<float4*>(out + vbase) = o;
      } else {
        out[vbase] = val0;
        if (vbase + 1 < V) out[vbase + 1] = val1;
        if (vbase + 2 < V) out[vbase + 2] = val2;
      }
    }

    // online stat update (vals identical across lanes; val0 always finite)
    const float gm = fmaxf(fmaxf(val0, val1), fmaxf(val2, val3));
    const float M2 = fmaxf(wm, gm);
    wsum = wsum * expf(wm - M2) +
           expf(val0 - M2) + expf(val1 - M2) + expf(val2 - M2) + expf(val3 - M2);
    wm = M2;
  }

  if (lane == 0) { stat_m[wv] = wm; stat_s[wv] = wsum; }
  __syncthreads();
  if (t == 0) {
    float M = stat_m[0], Ss = stat_s[0];
    #pragma unroll
    for (int i = 1; i < 8; ++i) {
      const float m2 = stat_m[i], s2 = stat_s[i];
      const float M2 = fmaxf(M, m2);
      Ss = Ss * expf(M - M2) + s2 * expf(m2 - M2);
      M = M2;
    }
    pmax[b] = M;
    psum[b] = Ss;
  }
}

// ============ kD: block-redundant stat reduce + subtract ============
// 99 blocks x 512 threads; thread t owns stat pair t (exactly KC_BLOCKS=512
// pairs -> every lane holds a FINITE value; no -inf enters the merges).
__global__ __launch_bounds__(512) void kD(
    const float* __restrict__ pmax,
    const float* __restrict__ psum,
    float* __restrict__ out)
{
  __shared__ float sm[8];
  __shared__ float ss[8];
  __shared__ float Tsh;
  const int t = threadIdx.x, lane = t & 63, wv = t >> 6;

  float dm = pmax[t];
  float dsv = psum[t];
  #pragma unroll
  for (int off = 32; off > 0; off >>= 1) {
    const float m2 = __shfl_xor(dm, off, 64);
    const float s2 = __shfl_xor(dsv, off, 64);
    const float M2 = fmaxf(dm, m2);
    dsv = dsv * expf(dm - M2) + s2 * expf(m2 - M2);
    dm = M2;
  }
  if (lane == 0) { sm[wv] = dm; ss[wv] = dsv; }
  __syncthreads();
  if (t == 0) {
    float M = sm[0], Ss = ss[0];
    #pragma unroll
    for (int i = 1; i < 8; ++i) {
      const float m2 = sm[i], s2 = ss[i];
      const float M2 = fmaxf(M, m2);
      Ss = Ss * expf(M - M2) + s2 * expf(m2 - M2);
      M = M2;
    }
    Tsh = M + logf(Ss);
  }
  __syncthreads();
  const float T = Tsh;
  const int i = blockIdx.x * 512 + t;
  if (i < V) out[i] -= T;
}

extern "C" void kernel_launch(void* const* d_in, const int* in_sizes, int n_in,
                              void* d_out, int out_size, void* d_ws, size_t ws_size,
                              hipStream_t stream) {
  const int*   token       = (const int*)d_in[0];
  const float* hidden      = (const float*)d_in[1];
  const float* enc         = (const float*)d_in[2];
  const float* embed_table = (const float*)d_in[3];
  const float* attn_w      = (const float*)d_in[4];
  const float* attn_b      = (const float*)d_in[5];
  const float* v_w         = (const float*)d_in[6];
  const float* w_ih        = (const float*)d_in[7];
  const float* w_hh        = (const float*)d_in[8];
  const float* b_ih        = (const float*)d_in[9];
  const float* b_hh        = (const float*)d_in[10];
  const float* out_w       = (const float*)d_in[11];
  const float* out_b       = (const float*)d_in[12];
  float* out = (float*)d_out;
  float* ws  = (float*)d_ws;

  // ws layout (floats)
  float* bpart = ws;           // 5120
  float* gie   = ws + 5120;    // 3072
  float* ghv   = ws + 8192;    // 3072
  float* hnew  = ws + 11264;   // 1024
  float* pmax  = ws + 12288;   // 512
  float* psum  = ws + 12800;   // 512

  kA<<<1792, 256, 0, stream>>>(token, hidden, enc, embed_table, attn_w, attn_b,
                               v_w, w_ih, w_hh, b_ih, b_hh, bpart, gie, ghv);
  kB<<<256, 256, 0, stream>>>(enc, bpart, w_ih, gie, ghv, hidden, hnew, out);
  kC<<<KC_BLOCKS, 512, 0, stream>>>(hnew, out_w, out_b, out, pmax, psum);
  kD<<<(V + 511) / 512, 512, 0, stream>>>(pmax, psum, out);
}